// Round 8
// baseline (50.068 us; speedup 1.0000x reference)
//
#include <hip/hip_runtime.h>
#include <math.h>

// Problem constants (match reference)
#define BB 64
#define HH 224
#define WW 224
#define CC 3

constexpr float FACTOR  = 0.2f;
constexpr float SCALE_K = 1.0f / 255.0f;
constexpr float TWO_PI_F = 6.283185307179586f;
constexpr float CX = (WW - 1) * 0.5f;            // 111.5
constexpr float CY = (HH - 1) * 0.5f;            // 111.5
constexpr int PIX = HH * WW;                     // 50176
constexpr int IMG_ELEMS = PIX * CC;              // 150528

constexpr int TILES_X = WW / 16;                 // 14
constexpr int TILES_PER_IMG = TILES_X * TILES_X; // 196
constexpr int NXCD = 8;
constexpr int NBLOCKS = BB * TILES_PER_IMG;      // 12544

constexpr int SSP = 33;   // SS row pitch in float4 (32 px + 1 pad)
constexpr int GP  = 24;   // G row pitch in float4
constexpr int ZP  = 18;   // Z row pitch in float4

typedef float f32x4v __attribute__((ext_vector_type(4), aligned(4)));

// Valid for i in [-n, 2n-1] — true for every coordinate in this pipeline.
__device__ __forceinline__ int reflect1(int i, int n) {
    i = (i < 0) ? (-1 - i) : i;
    return (i >= n) ? (2 * n - 1 - i) : i;
}

// Hull [lo,hi] of reflect1 over the integer range [a,b].
__device__ __forceinline__ void rhull(int a, int b, int n, int& lo, int& hi) {
    int ra = reflect1(a, n), rb = reflect1(b, n);
    lo = min(ra, rb); hi = max(ra, rb);
    if (a <= 0 && b >= -1) lo = 0;
    if (b >= n - 1 && a <= n) hi = n - 1;
}

// block i -> XCD i%8; batch b pinned to XCD b%8 (L2 locality per image).
__device__ __forceinline__ void decode_tile(int bid, int& b, int& tx, int& ty) {
    int xcd  = bid & (NXCD - 1);
    int slot = bid >> 3;
    int bi   = slot / TILES_PER_IMG;
    int t    = slot - bi * TILES_PER_IMG;
    b = xcd + bi * NXCD;
    ty = t / TILES_X;
    tx = t - ty * TILES_X;
}

// Fully fused rescale+rotate+zoom+translate+flip for one 16x16 output tile.
// Same bounds machinery as the passing R7 kernel; optimizations:
//  - all LDS tiles packed float4 (RGBX) -> 1 ds_read_b128 per tap
//  - separable coord precompute (rotate col/row terms; zoom x/y descriptors)
//  - dynamic G width (no wasted entries), row = float-reciprocal trick
//  - one-shot branchless 32x32 staging repack
__global__ __launch_bounds__(256)
void fused_kernel(const float* __restrict__ image, float* __restrict__ out,
                  const float* __restrict__ angle_u,
                  const float* __restrict__ zoom_u,
                  const float* __restrict__ shift_u,
                  const float* __restrict__ flip_u) {
    __shared__ float4 SS[32 * SSP];     // 16.9 KB staged 32x32 px, pre-scaled
    __shared__ float4 G[22 * GP];       // 8.4 KB rotate-stage values
    __shared__ float4 Z[17 * ZP];       // 4.9 KB zoom-stage values
    __shared__ float2 Xc2[22], Yc2[22]; // rotate separable terms
    __shared__ float4 XD[17], YD[17];   // zoom descriptors {frac, offA, offB}

    const int tid = threadIdx.x;
    int b, tx, ty;
    decode_tile(blockIdx.x, b, tx, ty);
    const int ox = tx * 16, oy = ty * 16;

    // --- per-batch params (exact reference expressions) ---
    const float theta = (2.0f * angle_u[b] - 1.0f) * FACTOR * TWO_PI_F;
    const float c = __cosf(theta), s = __sinf(theta);
    const float zh = 1.0f + (2.0f * zoom_u[2 * b + 0] - 1.0f) * FACTOR;
    const float zw = 1.0f + (2.0f * zoom_u[2 * b + 1] - 1.0f) * FACTOR;
    const float dy = ((2.0f * shift_u[2 * b + 0] - 1.0f) * FACTOR) * (float)HH;
    const float dx = ((2.0f * shift_u[2 * b + 1] - 1.0f) * FACTOR) * (float)WW;
    const bool flip = flip_u[b] > 0.5f;

    const float ndxf = floorf(-dx), ndyf = floorf(-dy);
    const int Kx = (int)ndxf, Ky = (int)ndyf;
    const float fx3 = -dx - ndxf, fy3 = -dy - ndyf;  // batch-uniform weights

    // --- bounds chain (identical to R7) ---
    const int Xmin = (flip ? WW - 16 - ox : ox) + Kx;
    const int Ymin = oy + Ky;
    int XrLo, XrHi, YrLo, YrHi;
    rhull(Xmin, Xmin + 16, WW, XrLo, XrHi);
    rhull(Ymin, Ymin + 16, HH, YrLo, YrHi);

    const int Gx0 = (int)floorf(zw * ((float)XrLo - CX) + CX);
    const int Gx1 = (int)floorf(zw * ((float)XrHi - CX) + CX) + 1;
    const int Gy0 = (int)floorf(zh * ((float)YrLo - CY) + CY);
    const int Gy1 = (int)floorf(zh * ((float)YrHi - CY) + CY) + 1;
    const int GW = min(Gx1 - Gx0 + 1, 22);
    const int GH = min(Gy1 - Gy0 + 1, 22);

    int RgxLo, RgxHi, RgyLo, RgyHi;
    rhull(Gx0, Gx1, WW, RgxLo, RgxHi);
    rhull(Gy0, Gy1, HH, RgyLo, RgyHi);

    const float rx0 = (float)RgxLo - CX, rx1 = (float)RgxHi - CX;
    const float ry0 = (float)RgyLo - CY, ry1 = (float)RgyHi - CY;
    const float xsmin = fminf(c * rx0, c * rx1) + fminf(-s * ry0, -s * ry1) + CX;
    const float xsmax = fmaxf(c * rx0, c * rx1) + fmaxf(-s * ry0, -s * ry1) + CX;
    const float ysmin = fminf(s * rx0, s * rx1) + fminf(c * ry0, c * ry1) + CY;
    const float ysmax = fmaxf(s * rx0, s * rx1) + fmaxf(c * ry0, c * ry1) + CY;
    int Cx0, Cx1, Cy0, Cy1;
    rhull((int)floorf(xsmin), (int)floorf(xsmax) + 1, WW, Cx0, Cx1);
    rhull((int)floorf(ysmin), (int)floorf(ysmax) + 1, HH, Cy0, Cy1);
    const int ColBase = min(Cx0, WW - 32);
    const int RowBase = min(Cy0, HH - 32);

    // --- phase 0: stage full 32x32 window, pre-scaled, branchless one-shot.
    // thread t: row r=t>>3, 4-px group g=t&7: 3 global b128 -> 4 LDS b128.
    {
        const int r = tid >> 3, g = tid & 7;
        const float* src = image + (size_t)b * IMG_ELEMS
                         + ((size_t)(RowBase + r) * WW + ColBase) * CC + g * 12;
        f32x4v v0 = *(const f32x4v*)(src);
        f32x4v v1 = *(const f32x4v*)(src + 4);
        f32x4v v2 = *(const f32x4v*)(src + 8);
        float4* row = &SS[r * SSP + g * 4];
        row[0] = make_float4(v0.x * SCALE_K, v0.y * SCALE_K, v0.z * SCALE_K, 0.f);
        row[1] = make_float4(v0.w * SCALE_K, v1.x * SCALE_K, v1.y * SCALE_K, 0.f);
        row[2] = make_float4(v1.z * SCALE_K, v1.w * SCALE_K, v2.x * SCALE_K, 0.f);
        row[3] = make_float4(v2.y * SCALE_K, v2.z * SCALE_K, v2.w * SCALE_K, 0.f);
    }

    // --- separable precompute (synced by the phase-1 barrier) ---
    if (tid < 22) {                               // rotate column terms
        int Rgx = reflect1(Gx0 + tid, WW);
        float t = (float)Rgx - CX;
        Xc2[tid] = make_float2(c * t, s * t);
    } else if (tid >= 32 && tid < 54) {           // rotate row terms
        int Rgy = reflect1(Gy0 + (tid - 32), HH);
        float t = (float)Rgy - CY;
        Yc2[tid - 32] = make_float2(CX - s * t, CY + c * t);
    } else if (tid >= 64 && tid < 81) {           // zoom x descriptors
        int ex = tid - 64;
        int Xr = reflect1(Xmin + ex, WW);
        float xs2 = zw * ((float)Xr - CX) + CX;   // exact reference expr
        float xf = floorf(xs2);
        int x20 = (int)xf;
        int cA = min(max(x20 - Gx0, 0), GW - 1);
        int cB = min(max(x20 + 1 - Gx0, 0), GW - 1);
        XD[ex] = make_float4(xs2 - xf, __int_as_float(cA), __int_as_float(cB), 0.f);
    } else if (tid >= 96 && tid < 113) {          // zoom y descriptors
        int ey = tid - 96;
        int Yr = reflect1(Ymin + ey, HH);
        float ys2 = zh * ((float)Yr - CY) + CY;
        float yf = floorf(ys2);
        int y20 = (int)yf;
        int rA = min(max(y20 - Gy0, 0), GH - 1);
        int rB = min(max(y20 + 1 - Gy0, 0), GH - 1);
        YD[ey] = make_float4(ys2 - yf, __int_as_float(rA * GP), __int_as_float(rB * GP), 0.f);
    }
    __syncthreads();

    // --- phase 1: rotate-stage values on the (dynamic) GWxGH zoom tap grid ---
    const int GN = GW * GH;
    const float rGW = 1.0f / (float)GW;
    for (int e = tid; e < GN; e += 256) {
        const int gy = (int)(((float)e + 0.5f) * rGW);   // exact: err 3e-5 << 1/(2GW)
        const int gx = e - gy * GW;
        const float2 xc = Xc2[gx];
        const float2 yc = Yc2[gy];
        const float xs = xc.x + yc.x;
        const float ys = xc.y + yc.y;
        const float xf = floorf(xs), yf = floorf(ys);
        const float fx = xs - xf, fy = ys - yf;
        const int x0 = (int)xf, y0 = (int)yf;
        const int c0 = min(max(reflect1(x0,     WW) - ColBase, 0), 31);
        const int c1 = min(max(reflect1(x0 + 1, WW) - ColBase, 0), 31);
        const int r0 = min(max(reflect1(y0,     HH) - RowBase, 0), 31);
        const int r1 = min(max(reflect1(y0 + 1, HH) - RowBase, 0), 31);
        const float4 A  = SS[r0 * SSP + c0];
        const float4 Bv = SS[r0 * SSP + c1];
        const float4 Cv = SS[r1 * SSP + c0];
        const float4 Dv = SS[r1 * SSP + c1];
        const float ofx = 1.0f - fx, ofy = 1.0f - fy;
        float4 res;
        res.x = (A.x * ofx + Bv.x * fx) * ofy + (Cv.x * ofx + Dv.x * fx) * fy;
        res.y = (A.y * ofx + Bv.y * fx) * ofy + (Cv.y * ofx + Dv.y * fx) * fy;
        res.z = (A.z * ofx + Bv.z * fx) * ofy + (Cv.z * ofx + Dv.z * fx) * fy;
        res.w = 0.f;
        G[gy * GP + gx] = res;
    }
    __syncthreads();

    // --- phase 2: zoom-stage values on the 17x17 translate window ---
    for (int e = tid; e < 289; e += 256) {
        const int ey = e / 17;                    // compile-time magic div
        const int ex = e - ey * 17;
        const float4 xd = XD[ex];
        const float4 yd = YD[ey];
        const int rA = __float_as_int(yd.y), rB = __float_as_int(yd.z);
        const int cA = __float_as_int(xd.y), cB = __float_as_int(xd.z);
        const float4 A  = G[rA + cA];
        const float4 Bv = G[rA + cB];
        const float4 Cv = G[rB + cA];
        const float4 Dv = G[rB + cB];
        const float fx2 = xd.x, fy2 = yd.x;
        const float ofx = 1.0f - fx2, ofy = 1.0f - fy2;
        float4 res;
        res.x = (A.x * ofx + Bv.x * fx2) * ofy + (Cv.x * ofx + Dv.x * fx2) * fy2;
        res.y = (A.y * ofx + Bv.y * fx2) * ofy + (Cv.y * ofx + Dv.y * fx2) * fy2;
        res.z = (A.z * ofx + Bv.z * fx2) * ofy + (Cv.z * ofx + Dv.z * fx2) * fy2;
        res.w = 0.f;
        Z[ey * ZP + ex] = res;
    }
    __syncthreads();

    // --- phase 3: translate blend + flip, write output ---
    const int lx = tid & 15, ly = tid >> 4;
    const int ix = flip ? (15 - lx) : lx;
    const float4 A  = Z[ly * ZP + ix];
    const float4 Bv = Z[ly * ZP + ix + 1];
    const float4 Cv = Z[(ly + 1) * ZP + ix];
    const float4 Dv = Z[(ly + 1) * ZP + ix + 1];
    const float ofx = 1.0f - fx3, ofy = 1.0f - fy3;
    float* o = out + ((size_t)b * PIX + (size_t)(oy + ly) * WW + (ox + lx)) * CC;
    o[0] = (A.x * ofx + Bv.x * fx3) * ofy + (Cv.x * ofx + Dv.x * fx3) * fy3;
    o[1] = (A.y * ofx + Bv.y * fx3) * ofy + (Cv.y * ofx + Dv.y * fx3) * fy3;
    o[2] = (A.z * ofx + Bv.z * fx3) * ofy + (Cv.z * ofx + Dv.z * fx3) * fy3;
}

extern "C" void kernel_launch(void* const* d_in, const int* in_sizes, int n_in,
                              void* d_out, int out_size, void* d_ws, size_t ws_size,
                              hipStream_t stream) {
    const float* image   = (const float*)d_in[0];
    const float* angle_u = (const float*)d_in[1];
    const float* zoom_u  = (const float*)d_in[2];
    const float* shift_u = (const float*)d_in[3];
    const float* flip_u  = (const float*)d_in[4];
    float* out = (float*)d_out;

    fused_kernel<<<NBLOCKS, 256, 0, stream>>>(image, out, angle_u, zoom_u,
                                              shift_u, flip_u);
}

// Round 9
// 36.574 us; speedup vs baseline: 1.3689x; 1.3689x over previous
//
#include <hip/hip_runtime.h>
#include <hip/hip_fp16.h>
#include <math.h>

// Problem constants (match reference)
#define BB 64
#define HH 224
#define WW 224
#define CC 3

constexpr float FACTOR  = 0.2f;
constexpr float SCALE_K = 1.0f / 255.0f;
constexpr float TWO_PI_F = 6.283185307179586f;
constexpr float CX = (WW - 1) * 0.5f;            // 111.5
constexpr float CY = (HH - 1) * 0.5f;            // 111.5
constexpr int PIX = HH * WW;                     // 50176
constexpr int IMG_ELEMS = PIX * CC;              // 150528

// K1: 16x16 tiles
constexpr int TILES_X = WW / 16;                 // 14
constexpr int TILES_PER_IMG = TILES_X * TILES_X; // 196
constexpr int NXCD = 8;
constexpr int NBLOCKS = BB * TILES_PER_IMG;      // 12544

// K2: 32x16 tiles
constexpr int T2X = WW / 32;                     // 7
constexpr int T2Y = HH / 16;                     // 14
constexpr int TILES2 = T2X * T2Y;                // 98
constexpr int NBLOCKS2 = BB * TILES2;            // 6272

constexpr int SZP = 50;   // staged-window row pitch (uint2 units; even)
constexpr int ZP2 = 34;   // Z row pitch (float4 units)

typedef float f32x4 __attribute__((ext_vector_type(4), aligned(4)));
typedef float f32x2 __attribute__((ext_vector_type(2), aligned(4)));
typedef unsigned int u32x4 __attribute__((ext_vector_type(4), aligned(8)));

// Valid for i in [-n, 2n-1] — true for every coordinate in this pipeline.
__device__ __forceinline__ int reflect1(int i, int n) {
    i = (i < 0) ? (-1 - i) : i;
    return (i >= n) ? (2 * n - 1 - i) : i;
}

// Hull [lo,hi] of reflect1 over the integer range [a,b].
__device__ __forceinline__ void rhull(int a, int b, int n, int& lo, int& hi) {
    int ra = reflect1(a, n), rb = reflect1(b, n);
    lo = min(ra, rb); hi = max(ra, rb);
    if (a <= 0 && b >= -1) lo = 0;
    if (b >= n - 1 && a <= n) hi = n - 1;
}

__device__ __forceinline__ float h2f(unsigned short u) {
    return __half2float(__ushort_as_half(u));
}

// ============================ K1: rescale + rotate ============================
// Verbatim from the best-measured (37.9us) R5 build: scattered row-pair
// vector gathers, fp16 RGBA tmp output. batch b pinned to XCD b%8.
__device__ __forceinline__ void decode_tile16(int bid, int& b, int& tx, int& ty) {
    int xcd  = bid & (NXCD - 1);
    int slot = bid >> 3;
    int bi   = slot / TILES_PER_IMG;
    int t    = slot - bi * TILES_PER_IMG;
    b = xcd + bi * NXCD;
    ty = t / TILES_X;
    tx = t - ty * TILES_X;
}

__global__ __launch_bounds__(256)
void rotate_kernel(const float* __restrict__ image, uint2* __restrict__ tmp,
                   const float* __restrict__ angle_u) {
    int b, tx, ty;
    decode_tile16(blockIdx.x, b, tx, ty);
    const int x = tx * 16 + (threadIdx.x & 15);
    const int y = ty * 16 + (threadIdx.x >> 4);

    float theta = (2.0f * angle_u[b] - 1.0f) * FACTOR * TWO_PI_F;
    float c = __cosf(theta), s = __sinf(theta);

    float rx = (float)x - CX;
    float ry = (float)y - CY;
    float xs = c * rx - s * ry + CX;
    float ys = s * rx + c * ry + CY;

    float x0f = floorf(xs), y0f = floorf(ys);
    float fx = xs - x0f, fy = ys - y0f;
    int x0 = (int)x0f, y0 = (int)y0f;
    int x0r = reflect1(x0,     WW);
    int x1r = reflect1(x0 + 1, WW);
    int y0r = reflect1(y0,     HH);
    int y1r = reflect1(y0 + 1, HH);

    int xl = min(x0r, x1r); xl = min(xl, WW - 2);
    const bool sA = (x0r != xl);           // A = floats [3..5] else [0..2]
    const bool sB = (x1r != xl);

    const float* img = image + (size_t)b * IMG_ELEMS;
    const float* rT = img + (y0r * WW + xl) * CC;
    const float* rB = img + (y1r * WW + xl) * CC;

    f32x4 t4 = *(const f32x4*)rT;
    f32x2 t2 = *(const f32x2*)(rT + 4);
    f32x4 b4 = *(const f32x4*)rB;
    f32x2 b2 = *(const f32x2*)(rB + 4);

    float TA[3] = { sA ? t4.w : t4.x, sA ? t2.x : t4.y, sA ? t2.y : t4.z };
    float TB[3] = { sB ? t4.w : t4.x, sB ? t2.x : t4.y, sB ? t2.y : t4.z };
    float BA[3] = { sA ? b4.w : b4.x, sA ? b2.x : b4.y, sA ? b2.y : b4.z };
    float BC[3] = { sB ? b4.w : b4.x, sB ? b2.x : b4.y, sB ? b2.y : b4.z };

    const float omfx = 1.0f - fx;
    const float omfy = 1.0f - fy;

    float o[3];
#pragma unroll
    for (int ch = 0; ch < CC; ++ch) {
        float top = TA[ch] * omfx + TB[ch] * fx;
        float bot = BA[ch] * omfx + BC[ch] * fx;
        o[ch] = (top * omfy + bot * fy) * SCALE_K;
    }

    unsigned u0 = __half_as_ushort(__float2half_rn(o[0]));
    unsigned u1 = __half_as_ushort(__float2half_rn(o[1]));
    unsigned u2 = __half_as_ushort(__float2half_rn(o[2]));
    uint2 v;
    v.x = u0 | (u1 << 16);
    v.y = u2;
    tmp[(size_t)b * PIX + y * WW + x] = v;
}

// ====================== K2: zoom + translate + flip ==========================
// 32x16 output tile. Coalesced LDS staging of the exact tmp window needed,
// descriptor-based separable zoom, fp32 Z in LDS, uniform translate blend.
__global__ __launch_bounds__(256)
void zoomshift_kernel(const uint2* __restrict__ tmp, float* __restrict__ out,
                      const float* __restrict__ zoom_u,
                      const float* __restrict__ shift_u,
                      const float* __restrict__ flip_u) {
    __shared__ uint2  Sz[24 * SZP];     // 9.4 KB staged tmp window (fp16 px)
    __shared__ float4 Z[17 * ZP2];      // 9.0 KB zoom-stage values
    __shared__ float4 XD[33], YD[17];   // zoom descriptors {frac, tapA, tapB}

    const int tid = threadIdx.x;
    const int xcd  = blockIdx.x & (NXCD - 1);
    const int slot = blockIdx.x >> 3;
    const int bi   = slot / TILES2;
    const int t    = slot - bi * TILES2;
    const int b    = xcd + bi * NXCD;
    const int ty   = t / T2X;
    const int tx   = t - ty * T2X;
    const int ox = tx * 32, oy = ty * 16;

    const float zh = 1.0f + (2.0f * zoom_u[2 * b + 0] - 1.0f) * FACTOR;
    const float zw = 1.0f + (2.0f * zoom_u[2 * b + 1] - 1.0f) * FACTOR;
    const float dy = ((2.0f * shift_u[2 * b + 0] - 1.0f) * FACTOR) * (float)HH;
    const float dx = ((2.0f * shift_u[2 * b + 1] - 1.0f) * FACTOR) * (float)WW;
    const bool flip = flip_u[b] > 0.5f;

    const float ndxf = floorf(-dx), ndyf = floorf(-dy);
    const int Kx = (int)ndxf, Ky = (int)ndyf;
    const float fx3 = -dx - ndxf, fy3 = -dy - ndyf;  // batch-uniform weights

    // translate window raw origin (flip folded into output x)
    const int Xmin = (flip ? WW - 32 - ox : ox) + Kx;
    const int Ymin = oy + Ky;

    // staged-window bounds: reflect hull -> zoom tap range (monotone) -> hull
    int XrLo, XrHi, YrLo, YrHi;
    rhull(Xmin, Xmin + 32, WW, XrLo, XrHi);
    rhull(Ymin, Ymin + 16, HH, YrLo, YrHi);
    const int Gx0 = (int)floorf(zw * ((float)XrLo - CX) + CX);
    const int Gx1 = (int)floorf(zw * ((float)XrHi - CX) + CX) + 1;
    const int Gy0 = (int)floorf(zh * ((float)YrLo - CY) + CY);
    const int Gy1 = (int)floorf(zh * ((float)YrHi - CY) + CY) + 1;
    int Cx0, Cx1, Cy0, Cy1;
    rhull(Gx0, Gx1, WW, Cx0, Cx1);     // width <= 41
    rhull(Gy0, Gy1, HH, Cy0, Cy1);     // height <= 22
    const int ColBase = max(min(Cx0, WW - 48), 0) & ~1;   // 48-px window, even
    const int RowBase = max(min(Cy0, HH - 24), 0);        // 24-row window

    // --- phase 0a: coalesced stage (24 rows x 24 x 16B groups = 576 items) ---
    const uint2* timg = tmp + (size_t)b * PIX;
    for (int id = tid; id < 576; id += 256) {
        const int row = id / 24;
        const int g   = id - row * 24;
        u32x4 v = *(const u32x4*)(timg + (size_t)(RowBase + row) * WW + ColBase + g * 2);
        *(u32x4*)(&Sz[row * SZP + g * 2]) = v;
    }

    // --- phase 0b: zoom descriptors (exact reference expressions) ---
    if (tid < 33) {
        const int Xr = reflect1(Xmin + tid, WW);
        const float xs2 = zw * ((float)Xr - CX) + CX;
        const float xf = floorf(xs2);
        const int x20 = (int)xf;
        const int cA = min(max(reflect1(x20,     WW) - ColBase, 0), 47);
        const int cB = min(max(reflect1(x20 + 1, WW) - ColBase, 0), 47);
        XD[tid] = make_float4(xs2 - xf, __int_as_float(cA), __int_as_float(cB), 0.f);
    } else if (tid >= 64 && tid < 81) {
        const int ey = tid - 64;
        const int Yr = reflect1(Ymin + ey, HH);
        const float ys2 = zh * ((float)Yr - CY) + CY;
        const float yf = floorf(ys2);
        const int y20 = (int)yf;
        const int rA = min(max(reflect1(y20,     HH) - RowBase, 0), 23) * SZP;
        const int rB = min(max(reflect1(y20 + 1, HH) - RowBase, 0), 23) * SZP;
        YD[ey] = make_float4(ys2 - yf, __int_as_float(rA), __int_as_float(rB), 0.f);
    }
    __syncthreads();

    // --- phase 1: Z[17][33] zoom-stage values, taps from LDS ---
    for (int e = tid; e < 17 * 33; e += 256) {
        const int ey = e / 33;
        const int ex = e - ey * 33;
        const float4 xd = XD[ex];
        const float4 yd = YD[ey];
        const int cA = __float_as_int(xd.y), cB = __float_as_int(xd.z);
        const int rA = __float_as_int(yd.y), rB = __float_as_int(yd.z);
        const uint2 va = Sz[rA + cA];
        const uint2 vb = Sz[rA + cB];
        const uint2 vc = Sz[rB + cA];
        const uint2 vd = Sz[rB + cB];
        const float fx2 = xd.x, fy2 = yd.x;
        const float ofx = 1.0f - fx2, ofy = 1.0f - fy2;
        float4 res;
        res.x = (h2f((unsigned short)(va.x & 0xffffu)) * ofx + h2f((unsigned short)(vb.x & 0xffffu)) * fx2) * ofy
              + (h2f((unsigned short)(vc.x & 0xffffu)) * ofx + h2f((unsigned short)(vd.x & 0xffffu)) * fx2) * fy2;
        res.y = (h2f((unsigned short)(va.x >> 16)) * ofx + h2f((unsigned short)(vb.x >> 16)) * fx2) * ofy
              + (h2f((unsigned short)(vc.x >> 16)) * ofx + h2f((unsigned short)(vd.x >> 16)) * fx2) * fy2;
        res.z = (h2f((unsigned short)(va.y & 0xffffu)) * ofx + h2f((unsigned short)(vb.y & 0xffffu)) * fx2) * ofy
              + (h2f((unsigned short)(vc.y & 0xffffu)) * ofx + h2f((unsigned short)(vd.y & 0xffffu)) * fx2) * fy2;
        res.w = 0.f;
        Z[ey * ZP2 + ex] = res;
    }
    __syncthreads();

    // --- phase 2: translate blend + flip, 2 px/thread, write output ---
    const float ofx = 1.0f - fx3, ofy = 1.0f - fy3;
#pragma unroll
    for (int i = 0; i < 2; ++i) {
        const int p  = tid + 256 * i;
        const int lx = p & 31, ly = p >> 5;
        const int ix = flip ? (31 - lx) : lx;
        const float4 A  = Z[ly * ZP2 + ix];
        const float4 Bv = Z[ly * ZP2 + ix + 1];
        const float4 Cv = Z[(ly + 1) * ZP2 + ix];
        const float4 Dv = Z[(ly + 1) * ZP2 + ix + 1];
        float* o = out + ((size_t)b * PIX + (size_t)(oy + ly) * WW + (ox + lx)) * CC;
        o[0] = (A.x * ofx + Bv.x * fx3) * ofy + (Cv.x * ofx + Dv.x * fx3) * fy3;
        o[1] = (A.y * ofx + Bv.y * fx3) * ofy + (Cv.y * ofx + Dv.y * fx3) * fy3;
        o[2] = (A.z * ofx + Bv.z * fx3) * ofy + (Cv.z * ofx + Dv.z * fx3) * fy3;
    }
}

extern "C" void kernel_launch(void* const* d_in, const int* in_sizes, int n_in,
                              void* d_out, int out_size, void* d_ws, size_t ws_size,
                              hipStream_t stream) {
    const float* image   = (const float*)d_in[0];
    const float* angle_u = (const float*)d_in[1];
    const float* zoom_u  = (const float*)d_in[2];
    const float* shift_u = (const float*)d_in[3];
    const float* flip_u  = (const float*)d_in[4];
    float* out = (float*)d_out;

    uint2* tmp = (uint2*)d_ws;   // B*H*W packed fp16 RGBA, 25.7 MB

    // pass 1: rescale + rotate   image -> tmp (fp16)
    rotate_kernel<<<NBLOCKS, 256, 0, stream>>>(image, tmp, angle_u);
    // pass 2+3 fused: zoom + translate + flip   tmp -> d_out
    zoomshift_kernel<<<NBLOCKS2, 256, 0, stream>>>(tmp, out, zoom_u, shift_u, flip_u);
}